// Round 12
// baseline (255.426 us; speedup 1.0000x reference)
//
#include <hip/hip_runtime.h>
#include <hip/hip_bf16.h>
#include <float.h>

#define D 64
#define K 512
#define HW 1024
#define DHW (D * HW)
#define N_PTS 65536
#define OUT_ELEMS (64 * D * HW)     /* 4,194,304 */
#define LOSS_OFF OUT_ELEMS
#define IDX_OFF (OUT_ELEMS + 1)
#define PTS_PER_BLOCK 64
#define NBLOCKS (N_PTS / PTS_PER_BLOCK)   /* 1024 */

typedef unsigned short ushort_t;
typedef unsigned long long ull_t;
typedef __attribute__((ext_vector_type(8))) short bf16x8;
typedef __attribute__((ext_vector_type(4))) float f32x4;

union U16x8 { uint4 u; bf16x8 v; ushort_t s[8]; };

__device__ __forceinline__ ushort_t f2bf(float v) {
    __hip_bfloat16 h = __float2bfloat16(v);
    return *reinterpret_cast<ushort_t*>(&h);
}
__device__ __forceinline__ float bf2f(ushort_t u) {
    unsigned int x = ((unsigned int)u) << 16;
    return *reinterpret_cast<float*>(&x);
}
__device__ __forceinline__ unsigned int f2ord(float s) {
    unsigned int u = __float_as_uint(s);
    return (u & 0x80000000u) ? ~u : (u | 0x80000000u);
}
__device__ __forceinline__ ull_t shfl_xor_u64(ull_t v, int mask) {
    unsigned int lo = (unsigned int)v, hi = (unsigned int)(v >> 32);
    lo = __shfl_xor((int)lo, mask);
    hi = __shfl_xor((int)hi, mask);
    return ((ull_t)hi << 32) | (ull_t)lo;
}

// ---------------------------------------------------------------------------
// numpy pairwise-sum (n=64): 8 accumulators over squares, combined
// ((r0+r1)+(r2+r3))+((r4+r5)+(r6+r7)); all adds/muls un-contracted.
// ---------------------------------------------------------------------------
__device__ __forceinline__ float np_sumsq64(const float* v) {
    float r[8];
#pragma unroll
    for (int j = 0; j < 8; ++j) r[j] = __fmul_rn(v[j], v[j]);
#pragma unroll
    for (int i = 8; i < D; i += 8) {
#pragma unroll
        for (int j = 0; j < 8; ++j)
            r[j] = __fadd_rn(r[j], __fmul_rn(v[i + j], v[i + j]));
    }
    return __fadd_rn(
        __fadd_rn(__fadd_rn(r[0], r[1]), __fadd_rn(r[2], r[3])),
        __fadd_rn(__fadd_rn(r[4], r[5]), __fadd_rn(r[6], r[7])));
}

// ---------------------------------------------------------------------------
// Prep (8 blocks x 64): thread = code k. e2 (numpy order); bhi fragments
// (layout verified r6): gid = kh*2048 + (k>>4)*64 + g*16 + (k&15);
// mpart[b] = block max |e - bf16(e)| (for the rigorous x.e_lo bound).
// ---------------------------------------------------------------------------
__global__ void vq_prep_kernel(const float* __restrict__ cb,
                               float* __restrict__ e2,
                               uint4* __restrict__ bhi,
                               float* __restrict__ mpart) {
    const int k = blockIdx.x * 64 + threadIdx.x;
    float row[D];
#pragma unroll
    for (int d = 0; d < D; ++d) row[d] = cb[k * D + d];
    e2[k] = np_sumsq64(row);

    float mmax = 0.f;
#pragma unroll
    for (int kh = 0; kh < 2; ++kh) {
#pragma unroll
        for (int g = 0; g < 4; ++g) {
            U16x8 u;
#pragma unroll
            for (int i = 0; i < 8; ++i) {
                float v = row[kh * 32 + g * 8 + i];
                ushort_t h = f2bf(v);
                u.s[i] = h;
                mmax = fmaxf(mmax, fabsf(__fsub_rn(v, bf2f(h))));
            }
            bhi[kh * 2048 + (k >> 4) * 64 + g * 16 + (k & 15)] = u.u;
        }
    }
#pragma unroll
    for (int off = 32; off > 0; off >>= 1)
        mmax = fmaxf(mmax, __shfl_down(mmax, off));
    if (threadIdx.x == 0) mpart[blockIdx.x] = mmax;
}

// ---------------------------------------------------------------------------
// Main VQ. Block = 64 points, 4 waves; wave w owns points [w*16, +16) vs ALL
// 512 codes in 2 chunks (c[16] reused -> 64 acc VGPRs; r11 post-mortem:
// c[2][16] + hoisted global B loads spilled ~26MB/dispatch). B staged
// per-chunk in LDS (32KB, bounds load live-ranges -> no spill, r6 evidence).
// 2 MFMA passes (xh+xl).eh; residual x.e_lo bounded: tau = 4e-5+2*sum|x|*M_EL.
// Online (s1,c1,s2) per lane, order-invariant butterfly merge, wave-local
// exact fallback (bit-exact numpy chain, r2-r11 validated). No atomics ->
// bit-deterministic across replays.
// ---------------------------------------------------------------------------
__global__ __launch_bounds__(256, 2) void vq_main_kernel(
        const float* __restrict__ z, const float* __restrict__ cb,
        const float* __restrict__ e2, const uint4* __restrict__ bhi,
        const float* __restrict__ mpart, float* __restrict__ out,
        float* __restrict__ partial) {
    __shared__ uint4 b_lds[2048];           // 32KB: one code-chunk of B
    __shared__ float x_lds[D][65];          // pad 65: conflict-free
    __shared__ float e2_lds[K];
    __shared__ float sabs[64];
    __shared__ int   ids[64];
    __shared__ int   need[64];
    __shared__ float wsum[4];

    const int t   = threadIdx.x;
    const int l   = t & 63;
    const int w   = t >> 6;
    const int p0  = w * 16;                 // this wave's 16 points
    const int n0  = blockIdx.x * PTS_PER_BLOCK;
    const int b   = n0 >> 10;
    const int hw0 = n0 & 1023;

    const float M_EL = fmaxf(fmaxf(fmaxf(mpart[0], mpart[1]),
                                   fmaxf(mpart[2], mpart[3])),
                             fmaxf(fmaxf(mpart[4], mpart[5]),
                                   fmaxf(mpart[6], mpart[7])));

    // ---- stage x (coalesced), e2 ----
    const float* zb = z + b * DHW + hw0;
#pragma unroll
    for (int i = 0; i < 16; ++i) {
        const int d = w * 16 + i;
        x_lds[d][l] = zb[d * HW + l];
    }
    e2_lds[t]       = e2[t];
    e2_lds[t + 256] = e2[t + 256];
    __syncthreads();

    // ---- sum|x| per point (wave-local): lane handles point p0+(l&15),
    // quadrant l>>4 sums dims [q*16, q*16+16); butterfly-add over q ----
    {
        const int pt = p0 + (l & 15);
        const int dq = (l >> 4) * 16;
        float sa = 0.f;
#pragma unroll
        for (int i = 0; i < 16; ++i) sa += fabsf(x_lds[dq + i][pt]);
        sa += __shfl_xor(sa, 16);
        sa += __shfl_xor(sa, 32);
        if (l < 16) sabs[p0 + l] = sa;
    }

    // ---- A fragments (hi + exact lo residual), layout verified r6 ----
    bf16x8 ah[2], al[2];
#pragma unroll
    for (int kh = 0; kh < 2; ++kh) {
        const int pt = p0 + (l & 15);
        const int d0 = kh * 32 + ((l >> 4) << 3);
        U16x8 uh, ul;
#pragma unroll
        for (int i = 0; i < 8; ++i) {
            float v = x_lds[d0 + i][pt];
            ushort_t h = f2bf(v);
            uh.s[i] = h;
            ul.s[i] = f2bf(__fsub_rn(v, bf2f(h)));
        }
        ah[kh] = uh.v;
        al[kh] = ul.v;
    }

    // ---- per-lane online top-2 state (4 rows r=0..3) ----
    float s1[4], s2[4];
    int   c1[4];
#pragma unroll
    for (int r = 0; r < 4; ++r) {
        s1[r] = -FLT_MAX; s2[r] = -FLT_MAX; c1[r] = 0x7fffffff;
    }

    for (int chunk = 0; chunk < 2; ++chunk) {
        // ---- stage this chunk's B (coalesced, 8 uint4/thread) ----
#pragma unroll
        for (int i = 0; i < 8; ++i) {
            const int j = i * 256 + t;              // 0..2047
            b_lds[j] = bhi[(j >> 10) * 2048 + chunk * 1024 + (j & 1023)];
        }
        __syncthreads();

        // ---- MFMA: c[nt] = (xh+xl).eh over 16 tiles ----
        f32x4 c[16];
#pragma unroll
        for (int nt = 0; nt < 16; ++nt) c[nt] = (f32x4){0.f, 0.f, 0.f, 0.f};
#pragma unroll
        for (int kh = 0; kh < 2; ++kh) {
#pragma unroll
            for (int nt = 0; nt < 16; ++nt) {
                U16x8 bu; bu.u = b_lds[kh * 1024 + nt * 64 + l];
                c[nt] = __builtin_amdgcn_mfma_f32_16x16x32_bf16(ah[kh], bu.v, c[nt], 0, 0, 0);
                c[nt] = __builtin_amdgcn_mfma_f32_16x16x32_bf16(al[kh], bu.v, c[nt], 0, 0, 0);
            }
        }

        // ---- score + online update (deterministic program order) ----
#pragma unroll
        for (int nt = 0; nt < 16; ++nt) {
            const int code = chunk * 256 + nt * 16 + (l & 15);
            const float B = e2_lds[code];
#pragma unroll
            for (int r = 0; r < 4; ++r) {
                const float s = __builtin_fmaf(B, -0.5f, c[nt][r]);
                if (s > s1[r]) {
                    s2[r] = s1[r]; s1[r] = s; c1[r] = code;
                } else if (s == s1[r]) {
                    c1[r] = min(c1[r], code);
                    s2[r] = s1[r];              // exact tie -> force fallback
                } else if (s > s2[r]) {
                    s2[r] = s;
                }
            }
        }
        __syncthreads();    // chunk's ds_reads done before restage
    }

    // ---- order-invariant butterfly merge over 16-lane code groups ----
#pragma unroll
    for (int mask = 1; mask < 16; mask <<= 1) {
#pragma unroll
        for (int r = 0; r < 4; ++r) {
            const float os1 = __shfl_xor(s1[r], mask);
            const float os2 = __shfl_xor(s2[r], mask);
            const int   oc1 = __shfl_xor(c1[r], mask);
            if (os1 > s1[r]) {
                s2[r] = fmaxf(s1[r], os2);
                s1[r] = os1; c1[r] = oc1;
            } else if (os1 == s1[r]) {
                c1[r] = min(c1[r], oc1);
                s2[r] = s1[r];                  // cross-lane tie -> fallback
            } else {
                s2[r] = fmaxf(s2[r], os1);
            }
        }
    }

    // ---- decision (wave-local): gap > tau -> winner; else flag ----
    if ((l & 15) == 0) {
#pragma unroll
        for (int r = 0; r < 4; ++r) {
            const int p = p0 + (l >> 4) * 4 + r;
            const float tau = 4.0e-5f + 2.0f * sabs[p] * M_EL;
            if (s1[r] - s2[r] > tau) {
                ids[p] = c1[r];
                out[IDX_OFF + n0 + p] = (float)c1[r];
                need[p] = 0;
            } else {
                need[p] = 1;
            }
        }
    }
    __syncthreads();

    // ---- wave-local exact fallback (bit-exact numpy chain; rare) ----
    for (int pp = 0; pp < 16; ++pp) {
        const int p = p0 + pp;
        if (!need[p]) continue;                 // uniform within wave
        float r8[8];
#pragma unroll
        for (int j = 0; j < 8; ++j) {
            const float v = x_lds[j][p];
            r8[j] = __fmul_rn(v, v);
        }
#pragma unroll
        for (int d = 8; d < D; ++d) {
            const float v = x_lds[d][p];
            r8[d & 7] = __fadd_rn(r8[d & 7], __fmul_rn(v, v));
        }
        const float Anp = __fadd_rn(
            __fadd_rn(__fadd_rn(r8[0], r8[1]), __fadd_rn(r8[2], r8[3])),
            __fadd_rn(__fadd_rn(r8[4], r8[5]), __fadd_rn(r8[6], r8[7])));
        ull_t best = ~0ull;
#pragma unroll
        for (int h = 0; h < 8; ++h) {
            const int k = l + h * 64;
            float acc = 0.f;
#pragma unroll
            for (int d = 0; d < D; ++d)
                acc = __builtin_fmaf(x_lds[d][p], cb[k * D + d], acc);
            const float dist = __fsub_rn(__fadd_rn(Anp, e2_lds[k]), 2.0f * acc);
            const ull_t key = ((ull_t)f2ord(dist) << 32) | (ull_t)k;
            if (key < best) best = key;         // ties -> lower k
        }
#pragma unroll
        for (int mask = 1; mask < 64; mask <<= 1) {
            const ull_t o = shfl_xor_u64(best, mask);
            if (o < best) best = o;
        }
        if (l == 0) {
            const int kwin = (int)(best & 0xffffffffull);
            ids[p] = kwin;
            out[IDX_OFF + n0 + p] = (float)kwin;
        }
    }
    __syncthreads();

    // ---- epilogue: out = fl(x + fl(q - x)), loss partials (direct gather:
    // codebook 128KB L2-hot; r8 showed cooperative gather gains nothing) ----
    float* ob = out + b * DHW + hw0;
    const int myid = ids[l];
    float lsum = 0.f;
#pragma unroll
    for (int i = 0; i < 16; ++i) {
        const int d  = w * 16 + i;
        const float xv   = x_lds[d][l];
        const float q    = cb[myid * D + d];
        const float diff = __fsub_rn(q, xv);
        lsum = __builtin_fmaf(diff, diff, lsum);
        ob[d * HW + l] = __fadd_rn(xv, diff);
    }
#pragma unroll
    for (int off = 32; off > 0; off >>= 1) lsum += __shfl_down(lsum, off);
    if (l == 0) wsum[w] = lsum;
    __syncthreads();
    if (t == 0)
        partial[blockIdx.x] = __fadd_rn(__fadd_rn(wsum[0], wsum[1]),
                                        __fadd_rn(wsum[2], wsum[3]));
}

// ---------------------------------------------------------------------------
// Loss kernel: reduce 1024 block partials -> loss = 1.25 * MSE
// ---------------------------------------------------------------------------
__global__ void vq_loss_kernel(const float* __restrict__ partial,
                               float* __restrict__ out) {
    __shared__ float sh[256];
    float s = 0.f;
#pragma unroll
    for (int i = 0; i < NBLOCKS / 256; ++i)
        s += partial[threadIdx.x + i * 256];
    sh[threadIdx.x] = s;
    __syncthreads();
    for (int off = 128; off > 0; off >>= 1) {
        if (threadIdx.x < off) sh[threadIdx.x] += sh[threadIdx.x + off];
        __syncthreads();
    }
    if (threadIdx.x == 0)
        out[LOSS_OFF] = 1.25f * sh[0] / (float)OUT_ELEMS;
}

extern "C" void kernel_launch(void* const* d_in, const int* in_sizes, int n_in,
                              void* d_out, int out_size, void* d_ws,
                              size_t ws_size, hipStream_t stream) {
    const float* z  = (const float*)d_in[0];   // [64, 64, 32, 32] f32
    const float* cb = (const float*)d_in[1];   // [512, 64] f32
    float* out = (float*)d_out;
    float* wsf = (float*)d_ws;
    float* e2      = wsf;                      // 512 f32
    float* partial = wsf + 512;                // 1024 f32
    float* mpart   = wsf + 1536;               // 8 f32
    uint4* bhi     = (uint4*)(wsf + 2048);     // 4096 uint4 = 64KB

    vq_prep_kernel<<<8, 64, 0, stream>>>(cb, e2, bhi, mpart);
    vq_main_kernel<<<NBLOCKS, 256, 0, stream>>>(z, cb, e2, bhi, mpart, out, partial);
    vq_loss_kernel<<<1, 256, 0, stream>>>(partial, out);
}